// Round 9
// baseline (1035.895 us; speedup 1.0000x reference)
//
#include <hip/hip_runtime.h>
#include <hip/hip_bf16.h>
#include <hip/hip_fp16.h>

#define NN 100000
#define EE 500000
#define NP 100096  // NN padded to 1564*64 = 391*256

typedef _Float16 f16;
typedef __attribute__((ext_vector_type(8))) _Float16 f16x8;
typedef __attribute__((ext_vector_type(4))) _Float16 f16x4;
typedef __attribute__((ext_vector_type(4))) float f32x4;

// ---------------- prep: W1 (L,128,256)->w1f [l][outcol][k] f16; W2 (L,256,128)->w2f [l][outcol][k] f16; bemb->f16
__global__ __launch_bounds__(256) void prep_kernel(const float* __restrict__ W1,
                                                   const float* __restrict__ W2,
                                                   const float* __restrict__ bemb,
                                                   f16* __restrict__ w1f,
                                                   f16* __restrict__ w2f,
                                                   f16* __restrict__ bembf) {
  int gid = blockIdx.x * 256 + threadIdx.x;
  if (gid < 163840) {
    int l = gid / 32768; int rem = gid % 32768;
    int k = rem / 256;   int n = rem % 256;
    w1f[l * 32768 + n * 128 + k] = (f16)W1[gid];
  } else if (gid < 327680) {
    int g = gid - 163840;
    int l = g / 32768; int rem = g % 32768;
    int j = rem / 128; int i = rem % 128;
    w2f[l * 32768 + i * 256 + j] = (f16)W2[g];
  } else if (gid < 343040) {
    int g = gid - 327680;
    bembf[g] = (f16)bemb[g];
  }
}

// ---------------- CSR build ----------------
__global__ __launch_bounds__(256) void zero_deg_kernel(int* __restrict__ deg) {
  int i = blockIdx.x * 256 + threadIdx.x;
  if (i < NN) deg[i] = 0;
}

__global__ __launch_bounds__(256) void hist_kernel(const int* __restrict__ ei, int* __restrict__ deg) {
  int e = blockIdx.x * 256 + threadIdx.x;
  if (e < EE) atomicAdd(&deg[ei[EE + e]], 1);
}

__global__ __launch_bounds__(256) void scan1_kernel(const int* __restrict__ deg,
                                                    int* __restrict__ offs,
                                                    int* __restrict__ bsum) {
  __shared__ int sh[256];
  int b = blockIdx.x, t = threadIdx.x;
  int base = b * 1024 + t * 4;
  int v[4];
  int s = 0;
#pragma unroll
  for (int i = 0; i < 4; ++i) { v[i] = (base + i < NN) ? deg[base + i] : 0; s += v[i]; }
  sh[t] = s;
  __syncthreads();
  for (int off = 1; off < 256; off <<= 1) {
    int x = (t >= off) ? sh[t - off] : 0;
    __syncthreads();
    sh[t] += x;
    __syncthreads();
  }
  int excl = sh[t] - s;
  if (t == 255) bsum[b] = sh[255];
  int run = excl;
#pragma unroll
  for (int i = 0; i < 4; ++i) {
    if (base + i < NN) offs[base + i] = run;
    run += v[i];
  }
}

__global__ void scan2_kernel(int* __restrict__ bsum, int nb) {
  if (threadIdx.x == 0 && blockIdx.x == 0) {
    int run = 0;
    for (int i = 0; i < nb; ++i) { int v = bsum[i]; bsum[i] = run; run += v; }
  }
}

__global__ __launch_bounds__(256) void scan3_kernel(int* __restrict__ offs,
                                                    const int* __restrict__ bsum,
                                                    int* __restrict__ cursor) {
  int i = blockIdx.x * 256 + threadIdx.x;
  if (i < NN) {
    int v = offs[i] + bsum[i >> 10];
    offs[i] = v;
    cursor[i] = v;
  } else if (i == NN) {
    offs[NN] = EE;
  }
}

// pk = src(17b) | a0<<17 | a1<<20 | a2<<23 ; wsrt = edge weight
__global__ __launch_bounds__(256) void scatter_kernel(const int* __restrict__ ei,
                                                      const int* __restrict__ ea,
                                                      const float* __restrict__ ew,
                                                      int* __restrict__ cursor,
                                                      int* __restrict__ pk,
                                                      float* __restrict__ wsrt) {
  int e = blockIdx.x * 256 + threadIdx.x;
  if (e >= EE) return;
  int dst = ei[EE + e];
  int pos = atomicAdd(&cursor[dst], 1);
  int src = ei[e];
  int a0 = ea[e * 3 + 0], a1 = ea[e * 3 + 1], a2 = ea[e * 3 + 2];
  pk[pos] = src | (a0 << 17) | (a1 << 20) | (a2 << 23);
  wsrt[pos] = ew[e];
}

// ---------------- zero the sliced stat accumulators (12288 f32) ----------------
__global__ __launch_bounds__(256) void zero_slices_kernel(float* __restrict__ p) {
  int i = blockIdx.x * 256 + threadIdx.x; // 12 blocks
  *(float4*)(p + i * 4) = float4{0.f, 0.f, 0.f, 0.f};
}

// ---------------- atom embedding: hf16[n,d] = (f16) sum_f atom_emb[f, x[n,f], d] ----------------
__global__ __launch_bounds__(256) void atom_kernel(const int* __restrict__ x,
                                                   const float* __restrict__ aemb,
                                                   f16* __restrict__ hf) {
  int gid = blockIdx.x * 256 + threadIdx.x;
  int n = gid >> 5, qq = gid & 31;
  if (n >= NN) return;
  float4 s = {0.f, 0.f, 0.f, 0.f};
#pragma unroll
  for (int f = 0; f < 9; ++f) {
    int xi = x[n * 9 + f];
    float4 v = *(const float4*)(aemb + (f * 120 + xi) * 128 + qq * 4);
    s.x += v.x; s.y += v.y; s.z += v.z; s.w += v.w;
  }
  f16x4 o;
  o[0] = (f16)s.x; o[1] = (f16)s.y; o[2] = (f16)s.z; o[3] = (f16)s.w;
  *(f16x4*)(hf + (long)n * 128 + qq * 4) = o;
}

// ---------------- edge aggregate (CSR, no atomics), fp16 gather:
// z[n] = (1+eps[l])*h[n] + sum relu(h[src]+bond_e)*w_e ; out f16; zero pad rows
__global__ __launch_bounds__(256) void edge_agg_kernel(const int* __restrict__ offs,
                                                       const int* __restrict__ pk,
                                                       const float* __restrict__ wsrt,
                                                       const f16* __restrict__ bembf, // + l*3072
                                                       const float* __restrict__ eps, int l,
                                                       const f16* __restrict__ hf,
                                                       f16* __restrict__ zb) {
  int gid = blockIdx.x * 256 + threadIdx.x; // NP*16 threads exactly
  int n = gid >> 4, d0 = (gid & 15) * 8;
  if (n >= NN) { // pad rows: zero so GEMM1 B-loads are branch-free
    f16x8 z = {0, 0, 0, 0, 0, 0, 0, 0};
    *(f16x8*)(zb + (long)n * 128 + d0) = z;
    return;
  }
  int s0 = offs[n], s1 = offs[n + 1];
  float e1 = 1.f + eps[l];
  f16x8 hn = *(const f16x8*)(hf + (long)n * 128 + d0);
  float acc[8];
#pragma unroll
  for (int i = 0; i < 8; ++i) acc[i] = e1 * (float)hn[i];
  for (int e = s0; e < s1; ++e) {
    int p = pk[e];
    float w = wsrt[e];
    int src = p & 131071;
    f16x8 b0 = *(const f16x8*)(bembf + (((p >> 17) & 7)) * 128 + d0);
    f16x8 b1 = *(const f16x8*)(bembf + (8 + ((p >> 20) & 7)) * 128 + d0);
    f16x8 b2 = *(const f16x8*)(bembf + (16 + ((p >> 23) & 7)) * 128 + d0);
    f16x8 hs = *(const f16x8*)(hf + (long)src * 128 + d0);
    f16x8 sm = hs + b0 + b1 + b2; // packed fp16 adds
#pragma unroll
    for (int i = 0; i < 8; ++i) {
      float sv = (float)sm[i];
      acc[i] += fmaxf(sv, 0.f) * w;
    }
  }
  f16x8 o;
#pragma unroll
  for (int i = 0; i < 8; ++i) o[i] = (f16)acc[i];
  *(f16x8*)(zb + (long)n * 128 + d0) = o;
}

// ---------------- GEMM1 (register-only fp16, transposed operands): t1 = z @ W1
// D[m=outcol][n=node]: A := weights frag, B := node frag. Lane holds 4 consecutive
// OUTCOLS per node -> f16x4 8B stores (4x fewer store instrs). No stats here.
__global__ __launch_bounds__(256) void gemm1_kernel(const f16* __restrict__ zb,
                                                    const f16* __restrict__ w1f,
                                                    f16* __restrict__ t1f) {
  const int tid = threadIdx.x;
  const int lane = tid & 63, w = tid >> 6;
  const int wr = w >> 1, wc = w & 1;
  const int m = lane & 15, q = lane >> 4;
  const int rbase = blockIdx.x * 64;
  const int colbase = blockIdx.y * 128 + wc * 64;
  f32x4 acc[4][2];
  const f32x4 zf = {0.f, 0.f, 0.f, 0.f};
#pragma unroll
  for (int a = 0; a < 4; ++a)
#pragma unroll
    for (int b = 0; b < 2; ++b) acc[a][b] = zf;

  long aoff[4], boff[2];
#pragma unroll
  for (int ct = 0; ct < 4; ++ct)
    aoff[ct] = (long)(colbase + ct * 16 + m) * 128 + q * 8;  // weights [outcol][k]
#pragma unroll
  for (int rt = 0; rt < 2; ++rt)
    boff[rt] = (long)(rbase + wr * 32 + rt * 16 + m) * 128 + q * 8; // z [node][k]

  f16x8 A[4][4], B[2][4];
#pragma unroll
  for (int ct = 0; ct < 4; ++ct)
#pragma unroll
    for (int c = 0; c < 4; ++c)
      A[ct][c] = *(const f16x8*)(w1f + aoff[ct] + c * 32);
#pragma unroll
  for (int rt = 0; rt < 2; ++rt)
#pragma unroll
    for (int c = 0; c < 4; ++c)
      B[rt][c] = *(const f16x8*)(zb + boff[rt] + c * 32);

#pragma unroll
  for (int c = 0; c < 4; ++c)
#pragma unroll
    for (int ct = 0; ct < 4; ++ct)
#pragma unroll
      for (int rt = 0; rt < 2; ++rt)
        acc[ct][rt] = __builtin_amdgcn_mfma_f32_16x16x32_f16(A[ct][c], B[rt][c], acc[ct][rt], 0, 0, 0);

  // epilogue: lane holds outcols colbase+ct*16+q*4..+3 for node rbase+wr*32+rt*16+m
#pragma unroll
  for (int ct = 0; ct < 4; ++ct)
#pragma unroll
    for (int rt = 0; rt < 2; ++rt) {
      int node = rbase + wr * 32 + rt * 16 + m;
      int col0 = colbase + ct * 16 + q * 4;
      f16x4 o;
      o[0] = (f16)acc[ct][rt][0]; o[1] = (f16)acc[ct][rt][1];
      o[2] = (f16)acc[ct][rt][2]; o[3] = (f16)acc[ct][rt][3];
      *(f16x4*)(t1f + (long)node * 256 + col0) = o;
    }
}

// ---------------- colstats 256: column sum/sumsq of t (NP x 256 f16), 16-sliced
__global__ __launch_bounds__(256) void colstats256_kernel(const f16* __restrict__ t,
                                                          float* __restrict__ sums,
                                                          float* __restrict__ sqs) {
  __shared__ float ls[2048], lq[2048];
  int tid = threadIdx.x;
  int c8 = tid & 31, ry = tid >> 5; // ry 0..7
  long rbase = (long)blockIdx.x * 256;
  float s[8], q2[8];
#pragma unroll
  for (int i = 0; i < 8; ++i) { s[i] = 0.f; q2[i] = 0.f; }
  for (int it = 0; it < 32; ++it) {
    long row = rbase + it * 8 + ry;
    f16x8 v = *(const f16x8*)(t + row * 256 + c8 * 8);
#pragma unroll
    for (int i = 0; i < 8; ++i) { float f = (float)v[i]; s[i] += f; q2[i] += f * f; }
  }
  *(float4*)(&ls[ry * 256 + c8 * 8])     = float4{s[0], s[1], s[2], s[3]};
  *(float4*)(&ls[ry * 256 + c8 * 8 + 4]) = float4{s[4], s[5], s[6], s[7]};
  *(float4*)(&lq[ry * 256 + c8 * 8])     = float4{q2[0], q2[1], q2[2], q2[3]};
  *(float4*)(&lq[ry * 256 + c8 * 8 + 4]) = float4{q2[4], q2[5], q2[6], q2[7]};
  __syncthreads();
  int col = tid;
  float ss = 0.f, qq = 0.f;
#pragma unroll
  for (int r = 0; r < 8; ++r) { ss += ls[r * 256 + col]; qq += lq[r * 256 + col]; }
  int slice = blockIdx.x & 15;
  unsafeAtomicAdd(&sums[slice * 256 + col], ss);
  unsafeAtomicAdd(&sqs[slice * 256 + col], qq);
}

// ---------------- colstats 128: column sum/sumsq of t (NP x 128 f16), 16-sliced
__global__ __launch_bounds__(256) void colstats128_kernel(const f16* __restrict__ t,
                                                          float* __restrict__ sums,
                                                          float* __restrict__ sqs) {
  __shared__ float ls[2048], lq[2048];
  int tid = threadIdx.x;
  int c8 = tid & 15, ry = tid >> 4; // ry 0..15
  long rbase = (long)blockIdx.x * 256;
  float s[8], q2[8];
#pragma unroll
  for (int i = 0; i < 8; ++i) { s[i] = 0.f; q2[i] = 0.f; }
  for (int it = 0; it < 16; ++it) {
    long row = rbase + it * 16 + ry;
    f16x8 v = *(const f16x8*)(t + row * 128 + c8 * 8);
#pragma unroll
    for (int i = 0; i < 8; ++i) { float f = (float)v[i]; s[i] += f; q2[i] += f * f; }
  }
  *(float4*)(&ls[ry * 128 + c8 * 8])     = float4{s[0], s[1], s[2], s[3]};
  *(float4*)(&ls[ry * 128 + c8 * 8 + 4]) = float4{s[4], s[5], s[6], s[7]};
  *(float4*)(&lq[ry * 128 + c8 * 8])     = float4{q2[0], q2[1], q2[2], q2[3]};
  *(float4*)(&lq[ry * 128 + c8 * 8 + 4]) = float4{q2[4], q2[5], q2[6], q2[7]};
  __syncthreads();
  if (tid < 128) {
    int col = tid;
    float ss = 0.f, qq = 0.f;
#pragma unroll
    for (int r = 0; r < 16; ++r) { ss += ls[r * 128 + col]; qq += lq[r * 128 + col]; }
    int slice = blockIdx.x & 15;
    unsafeAtomicAdd(&sums[slice * 128 + col], ss);
    unsafeAtomicAdd(&sqs[slice * 128 + col], qq);
  }
}

// ---------------- stats: reduce 16 slices, compute scale/shift, re-zero slices
__global__ void stats_kernel(float* __restrict__ sums, float* __restrict__ sqs,
                             const float* __restrict__ g, const float* __restrict__ bt,
                             float* __restrict__ scale, float* __restrict__ shift, int C) {
  int j = blockIdx.x * blockDim.x + threadIdx.x;
  if (j >= C) return;
  float s = 0.f, s2 = 0.f;
#pragma unroll
  for (int k = 0; k < 16; ++k) {
    s += sums[k * C + j]; s2 += sqs[k * C + j];
    sums[k * C + j] = 0.f; sqs[k * C + j] = 0.f; // ready for next layer
  }
  float mu = s * (1.f / NN);
  float var = s2 * (1.f / NN) - mu * mu;
  var = fmaxf(var, 0.f);
  float is = rsqrtf(var + 1e-5f);
  float sc = g[j] * is;
  scale[j] = sc;
  shift[j] = bt[j] - mu * sc;
}

// ---------------- bnapply (in-place): t1 <- relu(BN1(t1)) as f16; pad rows zeroed
__global__ __launch_bounds__(256) void bnapply_kernel(f16* __restrict__ t1f,
                                                      const float* __restrict__ scale1,
                                                      const float* __restrict__ shift1) {
  long idx = (long)(blockIdx.x * 256 + threadIdx.x) * 8; // NP*256 elems exactly
  int row = (int)(idx >> 8);
  f16x8 o;
  if (row >= NN) {
    f16x8 z = {0, 0, 0, 0, 0, 0, 0, 0};
    o = z; // zero pad rows: keeps gemm2 branch-free AND stats2 exact
  } else {
    int j0 = (int)(idx & 255);
    float4 sc0 = *(const float4*)(scale1 + j0);
    float4 sc1 = *(const float4*)(scale1 + j0 + 4);
    float4 sh0 = *(const float4*)(shift1 + j0);
    float4 sh1 = *(const float4*)(shift1 + j0 + 4);
    f16x8 u = *(const f16x8*)(t1f + idx);
    o[0] = (f16)fmaxf((float)u[0] * sc0.x + sh0.x, 0.f);
    o[1] = (f16)fmaxf((float)u[1] * sc0.y + sh0.y, 0.f);
    o[2] = (f16)fmaxf((float)u[2] * sc0.z + sh0.z, 0.f);
    o[3] = (f16)fmaxf((float)u[3] * sc0.w + sh0.w, 0.f);
    o[4] = (f16)fmaxf((float)u[4] * sc1.x + sh1.x, 0.f);
    o[5] = (f16)fmaxf((float)u[5] * sc1.y + sh1.y, 0.f);
    o[6] = (f16)fmaxf((float)u[6] * sc1.z + sh1.z, 0.f);
    o[7] = (f16)fmaxf((float)u[7] * sc1.w + sh1.w, 0.f);
  }
  *(f16x8*)(t1f + idx) = o;
}

// ---------------- GEMM2 (register-only fp16, transposed operands): t2 = a1 @ W2
// A := w2f frag (outcol), B := a1 frag (node). Out t2 f16 into zb via f16x4 stores.
__global__ __launch_bounds__(256) void gemm2_kernel(const f16* __restrict__ a1,
                                                    const f16* __restrict__ w2f,
                                                    f16* __restrict__ zb) {
  const int tid = threadIdx.x;
  const int lane = tid & 63, w = tid >> 6;
  const int wr = w >> 1, wc = w & 1;
  const int m = lane & 15, q = lane >> 4;
  const int rbase = blockIdx.x * 64;
  const int colbase = wc * 64;
  f32x4 acc[4][2];
  const f32x4 zf = {0.f, 0.f, 0.f, 0.f};
#pragma unroll
  for (int a = 0; a < 4; ++a)
#pragma unroll
    for (int b = 0; b < 2; ++b) acc[a][b] = zf;

  long aoff[4], boff[2];
#pragma unroll
  for (int ct = 0; ct < 4; ++ct)
    aoff[ct] = (long)(colbase + ct * 16 + m) * 256 + q * 8;  // w2f [outcol][k]
#pragma unroll
  for (int rt = 0; rt < 2; ++rt)
    boff[rt] = (long)(rbase + wr * 32 + rt * 16 + m) * 256 + q * 8; // a1 [node][k]

#pragma unroll
  for (int hh = 0; hh < 2; ++hh) { // K=256 in two halves of 4 chunks
    f16x8 A[4][4], B[2][4];
#pragma unroll
    for (int ct = 0; ct < 4; ++ct)
#pragma unroll
      for (int c = 0; c < 4; ++c)
        A[ct][c] = *(const f16x8*)(w2f + aoff[ct] + (hh * 4 + c) * 32);
#pragma unroll
    for (int rt = 0; rt < 2; ++rt)
#pragma unroll
      for (int c = 0; c < 4; ++c)
        B[rt][c] = *(const f16x8*)(a1 + boff[rt] + (hh * 4 + c) * 32);
#pragma unroll
    for (int c = 0; c < 4; ++c)
#pragma unroll
      for (int ct = 0; ct < 4; ++ct)
#pragma unroll
        for (int rt = 0; rt < 2; ++rt)
          acc[ct][rt] = __builtin_amdgcn_mfma_f32_16x16x32_f16(A[ct][c], B[rt][c], acc[ct][rt], 0, 0, 0);
  }
#pragma unroll
  for (int ct = 0; ct < 4; ++ct)
#pragma unroll
    for (int rt = 0; rt < 2; ++rt) {
      int node = rbase + wr * 32 + rt * 16 + m;
      int col0 = colbase + ct * 16 + q * 4;
      f16x4 o;
      o[0] = (f16)acc[ct][rt][0]; o[1] = (f16)acc[ct][rt][1];
      o[2] = (f16)acc[ct][rt][2]; o[3] = (f16)acc[ct][rt][3];
      *(f16x4*)(zb + (long)node * 128 + col0) = o;
    }
}

// ---------------- apply: y = BN2(t2); l<4: hf16 = relu(y); l==4: d_out = y (f32)
__global__ __launch_bounds__(256) void apply_kernel(const f16* __restrict__ zb,
                                                    const float* __restrict__ scale2,
                                                    const float* __restrict__ shift2,
                                                    int last,
                                                    f16* __restrict__ hf,
                                                    float* __restrict__ outp) {
  int gid = blockIdx.x * 256 + threadIdx.x;
  int n = gid >> 5, qq = gid & 31;
  if (n >= NN) return;
  f16x4 u = *(const f16x4*)(zb + (long)n * 128 + qq * 4);
  float4 sc = *(const float4*)(scale2 + qq * 4);
  float4 sh = *(const float4*)(shift2 + qq * 4);
  float y0 = (float)u[0] * sc.x + sh.x;
  float y1 = (float)u[1] * sc.y + sh.y;
  float y2 = (float)u[2] * sc.z + sh.z;
  float y3 = (float)u[3] * sc.w + sh.w;
  if (last) {
    float4 o = {y0, y1, y2, y3};
    *(float4*)(outp + (long)n * 128 + qq * 4) = o;
  } else {
    f16x4 o;
    o[0] = (f16)fmaxf(y0, 0.f); o[1] = (f16)fmaxf(y1, 0.f);
    o[2] = (f16)fmaxf(y2, 0.f); o[3] = (f16)fmaxf(y3, 0.f);
    *(f16x4*)(hf + (long)n * 128 + qq * 4) = o;
  }
}

extern "C" void kernel_launch(void* const* d_in, const int* in_sizes, int n_in,
                              void* d_out, int out_size, void* d_ws, size_t ws_size,
                              hipStream_t stream) {
  (void)in_sizes; (void)n_in; (void)out_size; (void)ws_size;
  const int*   x      = (const int*)d_in[0];
  const int*   ei     = (const int*)d_in[1];
  const int*   ea     = (const int*)d_in[2];
  const float* ew     = (const float*)d_in[3];
  const float* aemb   = (const float*)d_in[4];
  const float* bemb   = (const float*)d_in[5];
  const float* eps    = (const float*)d_in[6];
  const float* W1     = (const float*)d_in[7];
  const float* g1     = (const float*)d_in[9];
  const float* bt1    = (const float*)d_in[10];
  const float* W2     = (const float*)d_in[11];
  const float* g_out  = (const float*)d_in[13];
  const float* bt_out = (const float*)d_in[14];

  float* outp = (float*)d_out; // final f32 output, written only at l==4

  // ws layout (ends ~108.44 MB, same extent as round 8 — known in-bounds):
  char* ws = (char*)d_ws;
  f16*   hf    = (f16*)(ws);               // NP x 128 f16
  f16*   zb    = (f16*)(ws + 25624576);    // NP x 128 f16 — z / t2 alternately
  f16*   t1f   = (f16*)(ws + 51249152);    // NP x 256 f16 — bnapply'd in place
  f16*   w1f   = (f16*)(ws + 102498304);   // 327,680 B
  f16*   w2f   = (f16*)(ws + 102825984);   // 327,680 B
  f16*   bembf = (f16*)(ws + 103153664);   // 30,720 B
  float* ssbuf = (float*)(ws + 103184384); // 768 f32
  float* slices= (float*)(ws + 103187456); // 12,288 f32
  int*   deg    = (int*)(ws + 103236608);
  int*   offs   = (int*)(ws + 103636608);
  int*   cursor = (int*)(ws + 104036624);
  int*   bsum   = (int*)(ws + 104436624);
  int*   pk     = (int*)(ws + 104437024);
  float* wsrt   = (float*)(ws + 106437024); // ends 108,437,024

  float* scale1 = ssbuf;        float* shift1 = ssbuf + 256;
  float* scale2 = ssbuf + 512;  float* shift2 = ssbuf + 640;
  float* sum1s = slices;        // 16*256
  float* sq1s  = slices + 4096; // 16*256
  float* sum2s = slices + 8192; // 16*128
  float* sq2s  = slices + 10240;// 16*128

  prep_kernel<<<1340, 256, 0, stream>>>(W1, W2, bemb, w1f, w2f, bembf);
  zero_deg_kernel<<<391, 256, 0, stream>>>(deg);
  hist_kernel<<<1954, 256, 0, stream>>>(ei, deg);
  scan1_kernel<<<98, 256, 0, stream>>>(deg, offs, bsum);
  scan2_kernel<<<1, 64, 0, stream>>>(bsum, 98);
  scan3_kernel<<<392, 256, 0, stream>>>(offs, bsum, cursor);
  scatter_kernel<<<1954, 256, 0, stream>>>(ei, ea, ew, cursor, pk, wsrt);
  zero_slices_kernel<<<12, 256, 0, stream>>>(slices);
  atom_kernel<<<12500, 256, 0, stream>>>(x, aemb, hf);

  for (int l = 0; l < 5; ++l) {
    edge_agg_kernel<<<6256, 256, 0, stream>>>(offs, pk, wsrt, bembf + l * 3072, eps, l, hf, zb);
    gemm1_kernel<<<dim3(1564, 2), 256, 0, stream>>>(zb, w1f + l * 32768, t1f);
    colstats256_kernel<<<391, 256, 0, stream>>>(t1f, sum1s, sq1s);
    stats_kernel<<<1, 256, 0, stream>>>(sum1s, sq1s, g1 + l * 256, bt1 + l * 256, scale1, shift1, 256);
    bnapply_kernel<<<12512, 256, 0, stream>>>(t1f, scale1, shift1);
    gemm2_kernel<<<1564, 256, 0, stream>>>(t1f, w2f + l * 32768, zb);
    colstats128_kernel<<<391, 256, 0, stream>>>(zb, sum2s, sq2s);
    stats_kernel<<<1, 128, 0, stream>>>(sum2s, sq2s, g_out + l * 128, bt_out + l * 128, scale2, shift2, 128);
    apply_kernel<<<12500, 256, 0, stream>>>(zb, scale2, shift2, (l == 4) ? 1 : 0, hf, outp);
  }
}

// Round 10
// 1022.886 us; speedup vs baseline: 1.0127x; 1.0127x over previous
//
#include <hip/hip_runtime.h>
#include <hip/hip_bf16.h>
#include <hip/hip_fp16.h>

#define NN 100000
#define EE 500000
#define NP 100096  // NN padded to 1564*64 = 391*256

typedef _Float16 f16;
typedef __attribute__((ext_vector_type(8))) _Float16 f16x8;
typedef __attribute__((ext_vector_type(4))) _Float16 f16x4;
typedef __attribute__((ext_vector_type(4))) float f32x4;

// ---------------- prep: W1 (L,128,256)->w1f [l][outcol][k] f16; W2 (L,256,128)->w2f [l][outcol][k] f16; bemb->f16
__global__ __launch_bounds__(256) void prep_kernel(const float* __restrict__ W1,
                                                   const float* __restrict__ W2,
                                                   const float* __restrict__ bemb,
                                                   f16* __restrict__ w1f,
                                                   f16* __restrict__ w2f,
                                                   f16* __restrict__ bembf) {
  int gid = blockIdx.x * 256 + threadIdx.x;
  if (gid < 163840) {
    int l = gid / 32768; int rem = gid % 32768;
    int k = rem / 256;   int n = rem % 256;
    w1f[l * 32768 + n * 128 + k] = (f16)W1[gid];
  } else if (gid < 327680) {
    int g = gid - 163840;
    int l = g / 32768; int rem = g % 32768;
    int j = rem / 128; int i = rem % 128;
    w2f[l * 32768 + i * 256 + j] = (f16)W2[g];
  } else if (gid < 343040) {
    int g = gid - 327680;
    bembf[g] = (f16)bemb[g];
  }
}

// ---------------- CSR build ----------------
__global__ __launch_bounds__(256) void zero_deg_kernel(int* __restrict__ deg) {
  int i = blockIdx.x * 256 + threadIdx.x;
  if (i < NN) deg[i] = 0;
}

__global__ __launch_bounds__(256) void hist_kernel(const int* __restrict__ ei, int* __restrict__ deg) {
  int e = blockIdx.x * 256 + threadIdx.x;
  if (e < EE) atomicAdd(&deg[ei[EE + e]], 1);
}

__global__ __launch_bounds__(256) void scan1_kernel(const int* __restrict__ deg,
                                                    int* __restrict__ offs,
                                                    int* __restrict__ bsum) {
  __shared__ int sh[256];
  int b = blockIdx.x, t = threadIdx.x;
  int base = b * 1024 + t * 4;
  int v[4];
  int s = 0;
#pragma unroll
  for (int i = 0; i < 4; ++i) { v[i] = (base + i < NN) ? deg[base + i] : 0; s += v[i]; }
  sh[t] = s;
  __syncthreads();
  for (int off = 1; off < 256; off <<= 1) {
    int x = (t >= off) ? sh[t - off] : 0;
    __syncthreads();
    sh[t] += x;
    __syncthreads();
  }
  int excl = sh[t] - s;
  if (t == 255) bsum[b] = sh[255];
  int run = excl;
#pragma unroll
  for (int i = 0; i < 4; ++i) {
    if (base + i < NN) offs[base + i] = run;
    run += v[i];
  }
}

__global__ void scan2_kernel(int* __restrict__ bsum, int nb) {
  if (threadIdx.x == 0 && blockIdx.x == 0) {
    int run = 0;
    for (int i = 0; i < nb; ++i) { int v = bsum[i]; bsum[i] = run; run += v; }
  }
}

__global__ __launch_bounds__(256) void scan3_kernel(int* __restrict__ offs,
                                                    const int* __restrict__ bsum,
                                                    int* __restrict__ cursor) {
  int i = blockIdx.x * 256 + threadIdx.x;
  if (i < NN) {
    int v = offs[i] + bsum[i >> 10];
    offs[i] = v;
    cursor[i] = v;
  } else if (i == NN) {
    offs[NN] = EE;
  }
}

// pk = src(17b) | a0<<17 | a1<<20 | a2<<23 ; wsrt = edge weight
__global__ __launch_bounds__(256) void scatter_kernel(const int* __restrict__ ei,
                                                      const int* __restrict__ ea,
                                                      const float* __restrict__ ew,
                                                      int* __restrict__ cursor,
                                                      int* __restrict__ pk,
                                                      float* __restrict__ wsrt) {
  int e = blockIdx.x * 256 + threadIdx.x;
  if (e >= EE) return;
  int dst = ei[EE + e];
  int pos = atomicAdd(&cursor[dst], 1);
  int src = ei[e];
  int a0 = ea[e * 3 + 0], a1 = ea[e * 3 + 1], a2 = ea[e * 3 + 2];
  pk[pos] = src | (a0 << 17) | (a1 << 20) | (a2 << 23);
  wsrt[pos] = ew[e];
}

// ---------------- zero the sliced stat accumulators (12288 f32) ----------------
__global__ __launch_bounds__(256) void zero_slices_kernel(float* __restrict__ p) {
  int i = blockIdx.x * 256 + threadIdx.x; // 12 blocks
  *(float4*)(p + i * 4) = float4{0.f, 0.f, 0.f, 0.f};
}

// ---------------- atom embedding: hf16[n,d] = (f16) sum_f atom_emb[f, x[n,f], d] ----------------
__global__ __launch_bounds__(256) void atom_kernel(const int* __restrict__ x,
                                                   const float* __restrict__ aemb,
                                                   f16* __restrict__ hf) {
  int gid = blockIdx.x * 256 + threadIdx.x;
  int n = gid >> 5, qq = gid & 31;
  if (n >= NN) return;
  float4 s = {0.f, 0.f, 0.f, 0.f};
#pragma unroll
  for (int f = 0; f < 9; ++f) {
    int xi = x[n * 9 + f];
    float4 v = *(const float4*)(aemb + (f * 120 + xi) * 128 + qq * 4);
    s.x += v.x; s.y += v.y; s.z += v.z; s.w += v.w;
  }
  f16x4 o;
  o[0] = (f16)s.x; o[1] = (f16)s.y; o[2] = (f16)s.z; o[3] = (f16)s.w;
  *(f16x4*)(hf + (long)n * 128 + qq * 4) = o;
}

// ---------------- edge aggregate (CSR, no atomics), fp16 gather:
// z[n] = (1+eps[l])*h[n] + sum relu(h[src]+bond_e)*w_e ; out f16; zero pad rows
__global__ __launch_bounds__(256) void edge_agg_kernel(const int* __restrict__ offs,
                                                       const int* __restrict__ pk,
                                                       const float* __restrict__ wsrt,
                                                       const f16* __restrict__ bembf, // + l*3072
                                                       const float* __restrict__ eps, int l,
                                                       const f16* __restrict__ hf,
                                                       f16* __restrict__ zb) {
  int gid = blockIdx.x * 256 + threadIdx.x; // NP*16 threads exactly
  int n = gid >> 4, d0 = (gid & 15) * 8;
  if (n >= NN) { // pad rows: zero so GEMM1 B-loads are branch-free
    f16x8 z = {0, 0, 0, 0, 0, 0, 0, 0};
    *(f16x8*)(zb + (long)n * 128 + d0) = z;
    return;
  }
  int s0 = offs[n], s1 = offs[n + 1];
  float e1 = 1.f + eps[l];
  f16x8 hn = *(const f16x8*)(hf + (long)n * 128 + d0);
  float acc[8];
#pragma unroll
  for (int i = 0; i < 8; ++i) acc[i] = e1 * (float)hn[i];
  for (int e = s0; e < s1; ++e) {
    int p = pk[e];
    float w = wsrt[e];
    int src = p & 131071;
    f16x8 b0 = *(const f16x8*)(bembf + (((p >> 17) & 7)) * 128 + d0);
    f16x8 b1 = *(const f16x8*)(bembf + (8 + ((p >> 20) & 7)) * 128 + d0);
    f16x8 b2 = *(const f16x8*)(bembf + (16 + ((p >> 23) & 7)) * 128 + d0);
    f16x8 hs = *(const f16x8*)(hf + (long)src * 128 + d0);
    f16x8 sm = hs + b0 + b1 + b2; // packed fp16 adds
#pragma unroll
    for (int i = 0; i < 8; ++i) {
      float sv = (float)sm[i];
      acc[i] += fmaxf(sv, 0.f) * w;
    }
  }
  f16x8 o;
#pragma unroll
  for (int i = 0; i < 8; ++i) o[i] = (f16)acc[i];
  *(f16x8*)(zb + (long)n * 128 + d0) = o;
}

// ---------------- GEMM1 (register-only fp16, transposed operands) + fused col-stats:
// t1 = z @ W1. D[m=outcol][n=node]. Stats: node-dim is lane bits 0-3 -> shfl_xor reduce.
__global__ __launch_bounds__(256) void gemm1_kernel(const f16* __restrict__ zb,
                                                    const f16* __restrict__ w1f,
                                                    f16* __restrict__ t1f,
                                                    float* __restrict__ sum1s,
                                                    float* __restrict__ sq1s) {
  const int tid = threadIdx.x;
  const int lane = tid & 63, w = tid >> 6;
  const int wr = w >> 1, wc = w & 1;
  const int m = lane & 15, q = lane >> 4;
  const int rbase = blockIdx.x * 64;
  const int colbase = blockIdx.y * 128 + wc * 64;
  const int slice = blockIdx.x & 15;
  f32x4 acc[4][2];
  const f32x4 zf = {0.f, 0.f, 0.f, 0.f};
#pragma unroll
  for (int a = 0; a < 4; ++a)
#pragma unroll
    for (int b = 0; b < 2; ++b) acc[a][b] = zf;

  long aoff[4], boff[2];
#pragma unroll
  for (int ct = 0; ct < 4; ++ct)
    aoff[ct] = (long)(colbase + ct * 16 + m) * 128 + q * 8;  // weights [outcol][k]
#pragma unroll
  for (int rt = 0; rt < 2; ++rt)
    boff[rt] = (long)(rbase + wr * 32 + rt * 16 + m) * 128 + q * 8; // z [node][k]

  f16x8 A[4][4], B[2][4];
#pragma unroll
  for (int ct = 0; ct < 4; ++ct)
#pragma unroll
    for (int c = 0; c < 4; ++c)
      A[ct][c] = *(const f16x8*)(w1f + aoff[ct] + c * 32);
#pragma unroll
  for (int rt = 0; rt < 2; ++rt)
#pragma unroll
    for (int c = 0; c < 4; ++c)
      B[rt][c] = *(const f16x8*)(zb + boff[rt] + c * 32);

#pragma unroll
  for (int c = 0; c < 4; ++c)
#pragma unroll
    for (int ct = 0; ct < 4; ++ct)
#pragma unroll
      for (int rt = 0; rt < 2; ++rt)
        acc[ct][rt] = __builtin_amdgcn_mfma_f32_16x16x32_f16(A[ct][c], B[rt][c], acc[ct][rt], 0, 0, 0);

  // epilogue: f16x4 stores + fused column stats (pad-node acc is exactly 0)
#pragma unroll
  for (int ct = 0; ct < 4; ++ct) {
    float s4[4], q4[4];
#pragma unroll
    for (int i = 0; i < 4; ++i) {
      float v0 = acc[ct][0][i], v1 = acc[ct][1][i];
      s4[i] = v0 + v1;
      q4[i] = v0 * v0 + v1 * v1;
    }
#pragma unroll
    for (int rt = 0; rt < 2; ++rt) {
      int node = rbase + wr * 32 + rt * 16 + m;
      int col0 = colbase + ct * 16 + q * 4;
      f16x4 o;
      o[0] = (f16)acc[ct][rt][0]; o[1] = (f16)acc[ct][rt][1];
      o[2] = (f16)acc[ct][rt][2]; o[3] = (f16)acc[ct][rt][3];
      *(f16x4*)(t1f + (long)node * 256 + col0) = o;
    }
    // reduce over m (lane bits 0-3)
#pragma unroll
    for (int msk = 1; msk < 16; msk <<= 1)
#pragma unroll
      for (int i = 0; i < 4; ++i) {
        s4[i] += __shfl_xor(s4[i], msk);
        q4[i] += __shfl_xor(q4[i], msk);
      }
    if (m == 0) {
      int col0 = colbase + ct * 16 + q * 4;
#pragma unroll
      for (int i = 0; i < 4; ++i) {
        unsafeAtomicAdd(&sum1s[slice * 256 + col0 + i], s4[i]);
        unsafeAtomicAdd(&sq1s[slice * 256 + col0 + i], q4[i]);
      }
    }
  }
}

// ---------------- stats: reduce 16 slices, compute scale/shift, re-zero slices
__global__ void stats_kernel(float* __restrict__ sums, float* __restrict__ sqs,
                             const float* __restrict__ g, const float* __restrict__ bt,
                             float* __restrict__ scale, float* __restrict__ shift, int C) {
  int j = blockIdx.x * blockDim.x + threadIdx.x;
  if (j >= C) return;
  float s = 0.f, s2 = 0.f;
#pragma unroll
  for (int k = 0; k < 16; ++k) {
    s += sums[k * C + j]; s2 += sqs[k * C + j];
    sums[k * C + j] = 0.f; sqs[k * C + j] = 0.f; // ready for next layer
  }
  float mu = s * (1.f / NN);
  float var = s2 * (1.f / NN) - mu * mu;
  var = fmaxf(var, 0.f);
  float is = rsqrtf(var + 1e-5f);
  float sc = g[j] * is;
  scale[j] = sc;
  shift[j] = bt[j] - mu * sc;
}

// ---------------- GEMM2 (register-only fp16, transposed operands) + fused BN1/relu on B + fused stats:
// t2 = relu(BN1(t1)) @ W2. B frags get BN applied in-register; pad nodes zeroed.
__global__ __launch_bounds__(256) void gemm2_kernel(const f16* __restrict__ t1f,
                                                    const float* __restrict__ scale1,
                                                    const float* __restrict__ shift1,
                                                    const f16* __restrict__ w2f,
                                                    f16* __restrict__ zb,
                                                    float* __restrict__ sum2s,
                                                    float* __restrict__ sq2s) {
  const int tid = threadIdx.x;
  const int lane = tid & 63, w = tid >> 6;
  const int wr = w >> 1, wc = w & 1;
  const int m = lane & 15, q = lane >> 4;
  const int rbase = blockIdx.x * 64;
  const int colbase = wc * 64;
  const int slice = blockIdx.x & 15;
  f32x4 acc[4][2];
  const f32x4 zf = {0.f, 0.f, 0.f, 0.f};
#pragma unroll
  for (int a = 0; a < 4; ++a)
#pragma unroll
    for (int b = 0; b < 2; ++b) acc[a][b] = zf;

  long aoff[4], boff[2];
  bool nok[2];
#pragma unroll
  for (int ct = 0; ct < 4; ++ct)
    aoff[ct] = (long)(colbase + ct * 16 + m) * 256 + q * 8;  // w2f [outcol][k]
#pragma unroll
  for (int rt = 0; rt < 2; ++rt) {
    int node = rbase + wr * 32 + rt * 16 + m;
    nok[rt] = node < NN; // pad nodes: BN shift would make them nonzero -> must zero
    boff[rt] = (long)node * 256 + q * 8;
  }

#pragma unroll
  for (int hh = 0; hh < 2; ++hh) { // K=256 in two halves of 4 chunks
    f16x8 A[4][4], B[2][4];
#pragma unroll
    for (int ct = 0; ct < 4; ++ct)
#pragma unroll
      for (int c = 0; c < 4; ++c)
        A[ct][c] = *(const f16x8*)(w2f + aoff[ct] + (hh * 4 + c) * 32);
#pragma unroll
    for (int rt = 0; rt < 2; ++rt)
#pragma unroll
      for (int c = 0; c < 4; ++c) {
        int cc = hh * 4 + c;
        f16x8 u = *(const f16x8*)(t1f + boff[rt] + cc * 32);
        int k0 = cc * 32 + q * 8;
        float4 sc0 = *(const float4*)(scale1 + k0);
        float4 sc1 = *(const float4*)(scale1 + k0 + 4);
        float4 sh0 = *(const float4*)(shift1 + k0);
        float4 sh1 = *(const float4*)(shift1 + k0 + 4);
        f16x8 o;
        o[0] = (f16)fmaxf((float)u[0] * sc0.x + sh0.x, 0.f);
        o[1] = (f16)fmaxf((float)u[1] * sc0.y + sh0.y, 0.f);
        o[2] = (f16)fmaxf((float)u[2] * sc0.z + sh0.z, 0.f);
        o[3] = (f16)fmaxf((float)u[3] * sc0.w + sh0.w, 0.f);
        o[4] = (f16)fmaxf((float)u[4] * sc1.x + sh1.x, 0.f);
        o[5] = (f16)fmaxf((float)u[5] * sc1.y + sh1.y, 0.f);
        o[6] = (f16)fmaxf((float)u[6] * sc1.z + sh1.z, 0.f);
        o[7] = (f16)fmaxf((float)u[7] * sc1.w + sh1.w, 0.f);
        if (!nok[rt]) {
          f16x8 z = {0, 0, 0, 0, 0, 0, 0, 0};
          o = z;
        }
        B[rt][c] = o;
      }
#pragma unroll
    for (int c = 0; c < 4; ++c)
#pragma unroll
      for (int ct = 0; ct < 4; ++ct)
#pragma unroll
        for (int rt = 0; rt < 2; ++rt)
          acc[ct][rt] = __builtin_amdgcn_mfma_f32_16x16x32_f16(A[ct][c], B[rt][c], acc[ct][rt], 0, 0, 0);
  }
  // epilogue: f16x4 stores + fused column stats (pad nodes have acc==0)
#pragma unroll
  for (int ct = 0; ct < 4; ++ct) {
    float s4[4], q4[4];
#pragma unroll
    for (int i = 0; i < 4; ++i) {
      float v0 = acc[ct][0][i], v1 = acc[ct][1][i];
      s4[i] = v0 + v1;
      q4[i] = v0 * v0 + v1 * v1;
    }
#pragma unroll
    for (int rt = 0; rt < 2; ++rt) {
      int node = rbase + wr * 32 + rt * 16 + m;
      int col0 = colbase + ct * 16 + q * 4;
      f16x4 o;
      o[0] = (f16)acc[ct][rt][0]; o[1] = (f16)acc[ct][rt][1];
      o[2] = (f16)acc[ct][rt][2]; o[3] = (f16)acc[ct][rt][3];
      *(f16x4*)(zb + (long)node * 128 + col0) = o;
    }
#pragma unroll
    for (int msk = 1; msk < 16; msk <<= 1)
#pragma unroll
      for (int i = 0; i < 4; ++i) {
        s4[i] += __shfl_xor(s4[i], msk);
        q4[i] += __shfl_xor(q4[i], msk);
      }
    if (m == 0) {
      int col0 = colbase + ct * 16 + q * 4;
#pragma unroll
      for (int i = 0; i < 4; ++i) {
        unsafeAtomicAdd(&sum2s[slice * 128 + col0 + i], s4[i]);
        unsafeAtomicAdd(&sq2s[slice * 128 + col0 + i], q4[i]);
      }
    }
  }
}

// ---------------- apply: y = BN2(t2); l<4: hf16 = relu(y); l==4: d_out = y (f32)
__global__ __launch_bounds__(256) void apply_kernel(const f16* __restrict__ zb,
                                                    const float* __restrict__ scale2,
                                                    const float* __restrict__ shift2,
                                                    int last,
                                                    f16* __restrict__ hf,
                                                    float* __restrict__ outp) {
  int gid = blockIdx.x * 256 + threadIdx.x;
  int n = gid >> 5, qq = gid & 31;
  if (n >= NN) return;
  f16x4 u = *(const f16x4*)(zb + (long)n * 128 + qq * 4);
  float4 sc = *(const float4*)(scale2 + qq * 4);
  float4 sh = *(const float4*)(shift2 + qq * 4);
  float y0 = (float)u[0] * sc.x + sh.x;
  float y1 = (float)u[1] * sc.y + sh.y;
  float y2 = (float)u[2] * sc.z + sh.z;
  float y3 = (float)u[3] * sc.w + sh.w;
  if (last) {
    float4 o = {y0, y1, y2, y3};
    *(float4*)(outp + (long)n * 128 + qq * 4) = o;
  } else {
    f16x4 o;
    o[0] = (f16)fmaxf(y0, 0.f); o[1] = (f16)fmaxf(y1, 0.f);
    o[2] = (f16)fmaxf(y2, 0.f); o[3] = (f16)fmaxf(y3, 0.f);
    *(f16x4*)(hf + (long)n * 128 + qq * 4) = o;
  }
}

extern "C" void kernel_launch(void* const* d_in, const int* in_sizes, int n_in,
                              void* d_out, int out_size, void* d_ws, size_t ws_size,
                              hipStream_t stream) {
  (void)in_sizes; (void)n_in; (void)out_size; (void)ws_size;
  const int*   x      = (const int*)d_in[0];
  const int*   ei     = (const int*)d_in[1];
  const int*   ea     = (const int*)d_in[2];
  const float* ew     = (const float*)d_in[3];
  const float* aemb   = (const float*)d_in[4];
  const float* bemb   = (const float*)d_in[5];
  const float* eps    = (const float*)d_in[6];
  const float* W1     = (const float*)d_in[7];
  const float* g1     = (const float*)d_in[9];
  const float* bt1    = (const float*)d_in[10];
  const float* W2     = (const float*)d_in[11];
  const float* g_out  = (const float*)d_in[13];
  const float* bt_out = (const float*)d_in[14];

  float* outp = (float*)d_out; // final f32 output, written only at l==4

  // ws layout (ends ~108.44 MB, same extent as rounds 8/9 — known in-bounds):
  char* ws = (char*)d_ws;
  f16*   hf    = (f16*)(ws);               // NP x 128 f16
  f16*   zb    = (f16*)(ws + 25624576);    // NP x 128 f16 — z / t2 alternately
  f16*   t1f   = (f16*)(ws + 51249152);    // NP x 256 f16 (raw t1; BN applied in gemm2)
  f16*   w1f   = (f16*)(ws + 102498304);   // 327,680 B
  f16*   w2f   = (f16*)(ws + 102825984);   // 327,680 B
  f16*   bembf = (f16*)(ws + 103153664);   // 30,720 B
  float* ssbuf = (float*)(ws + 103184384); // 768 f32
  float* slices= (float*)(ws + 103187456); // 12,288 f32
  int*   deg    = (int*)(ws + 103236608);
  int*   offs   = (int*)(ws + 103636608);
  int*   cursor = (int*)(ws + 104036624);
  int*   bsum   = (int*)(ws + 104436624);
  int*   pk     = (int*)(ws + 104437024);
  float* wsrt   = (float*)(ws + 106437024); // ends 108,437,024

  float* scale1 = ssbuf;        float* shift1 = ssbuf + 256;
  float* scale2 = ssbuf + 512;  float* shift2 = ssbuf + 640;
  float* sum1s = slices;        // 16*256
  float* sq1s  = slices + 4096; // 16*256
  float* sum2s = slices + 8192; // 16*128
  float* sq2s  = slices + 10240;// 16*128

  prep_kernel<<<1340, 256, 0, stream>>>(W1, W2, bemb, w1f, w2f, bembf);
  zero_deg_kernel<<<391, 256, 0, stream>>>(deg);
  hist_kernel<<<1954, 256, 0, stream>>>(ei, deg);
  scan1_kernel<<<98, 256, 0, stream>>>(deg, offs, bsum);
  scan2_kernel<<<1, 64, 0, stream>>>(bsum, 98);
  scan3_kernel<<<392, 256, 0, stream>>>(offs, bsum, cursor);
  scatter_kernel<<<1954, 256, 0, stream>>>(ei, ea, ew, cursor, pk, wsrt);
  zero_slices_kernel<<<12, 256, 0, stream>>>(slices);
  atom_kernel<<<12500, 256, 0, stream>>>(x, aemb, hf);

  for (int l = 0; l < 5; ++l) {
    edge_agg_kernel<<<6256, 256, 0, stream>>>(offs, pk, wsrt, bembf + l * 3072, eps, l, hf, zb);
    gemm1_kernel<<<dim3(1564, 2), 256, 0, stream>>>(zb, w1f + l * 32768, t1f, sum1s, sq1s);
    stats_kernel<<<1, 256, 0, stream>>>(sum1s, sq1s, g1 + l * 256, bt1 + l * 256, scale1, shift1, 256);
    gemm2_kernel<<<1564, 256, 0, stream>>>(t1f, scale1, shift1, w2f + l * 32768, zb, sum2s, sq2s);
    stats_kernel<<<1, 128, 0, stream>>>(sum2s, sq2s, g_out + l * 128, bt_out + l * 128, scale2, shift2, 128);
    apply_kernel<<<12500, 256, 0, stream>>>(zb, scale2, shift2, (l == 4) ? 1 : 0, hf, outp);
  }
}